// Round 1
// baseline (144.111 us; speedup 1.0000x reference)
//
#include <hip/hip_runtime.h>
#include <cstdint>
#include <math.h>

// Problem constants (from reference): B=128 rows, V=128000 vocab.
#define BB 128
#define VV 128000
#define SPLITS 8                 // segments per row -> 1024 blocks total
#define CHUNK (VV / SPLITS)      // 16000, divisible by 4 (float4) and by TPB*4
#define TPB 256

__device__ __forceinline__ void combine(float& bv, int& bi, float v, int i) {
    // argmax with FIRST-occurrence tie-break (smaller index wins ties)
    if (v > bv || (v == bv && i < bi)) { bv = v; bi = i; }
}

__global__ __launch_bounds__(TPB) void sampler_partial(
    const float* __restrict__ logits,
    const float* __restrict__ temps,
    const float* __restrict__ noise,
    float* __restrict__ pmax,
    int*   __restrict__ pidx)
{
    const int blk = blockIdx.x;
    const int row = blk / SPLITS;
    const int seg = blk % SPLITS;

    const float t = temps[row];
    const bool greedy = (t == 0.0f);
    const float invt = greedy ? 1.0f : (1.0f / t);

    const float* lrow = logits + (size_t)row * VV;
    const float* nrow = noise  + (size_t)row * VV;

    const int start = seg * CHUNK;
    const int end   = start + CHUNK;

    float bv = -INFINITY;
    int   bi = 0x7fffffff;

    if (greedy) {
        // greedy row: score = logits; skip the noise read entirely (saves HBM)
        for (int i = start + (int)threadIdx.x * 4; i < end; i += TPB * 4) {
            float4 l = *reinterpret_cast<const float4*>(lrow + i);
            combine(bv, bi, l.x, i + 0);
            combine(bv, bi, l.y, i + 1);
            combine(bv, bi, l.z, i + 2);
            combine(bv, bi, l.w, i + 3);
        }
    } else {
        for (int i = start + (int)threadIdx.x * 4; i < end; i += TPB * 4) {
            float4 l = *reinterpret_cast<const float4*>(lrow + i);
            float4 e = *reinterpret_cast<const float4*>(nrow + i);
            float s0 = l.x * invt - logf(fmaxf(e.x, 1e-10f));
            float s1 = l.y * invt - logf(fmaxf(e.y, 1e-10f));
            float s2 = l.z * invt - logf(fmaxf(e.z, 1e-10f));
            float s3 = l.w * invt - logf(fmaxf(e.w, 1e-10f));
            combine(bv, bi, s0, i + 0);
            combine(bv, bi, s1, i + 1);
            combine(bv, bi, s2, i + 2);
            combine(bv, bi, s3, i + 3);
        }
    }

    // wave64 shuffle reduction
    #pragma unroll
    for (int off = 32; off > 0; off >>= 1) {
        float ov = __shfl_down(bv, off, 64);
        int   oi = __shfl_down(bi, off, 64);
        combine(bv, bi, ov, oi);
    }

    __shared__ float sv[TPB / 64];
    __shared__ int   si[TPB / 64];
    const int lane = threadIdx.x & 63;
    const int wave = threadIdx.x >> 6;
    if (lane == 0) { sv[wave] = bv; si[wave] = bi; }
    __syncthreads();
    if (threadIdx.x == 0) {
        #pragma unroll
        for (int w = 1; w < TPB / 64; ++w) combine(bv, bi, sv[w], si[w]);
        pmax[blk] = bv;
        pidx[blk] = bi;
    }
}

__global__ __launch_bounds__(128) void sampler_reduce(
    const float* __restrict__ pmax,
    const int*   __restrict__ pidx,
    int* __restrict__ out)
{
    const int r = blockIdx.x * blockDim.x + threadIdx.x;
    if (r < BB) {
        float bv = -INFINITY;
        int   bi = 0x7fffffff;
        #pragma unroll
        for (int s = 0; s < SPLITS; ++s)
            combine(bv, bi, pmax[r * SPLITS + s], pidx[r * SPLITS + s]);
        out[r] = bi;
    }
}

extern "C" void kernel_launch(void* const* d_in, const int* in_sizes, int n_in,
                              void* d_out, int out_size, void* d_ws, size_t ws_size,
                              hipStream_t stream) {
    const float* logits = (const float*)d_in[0];   // [B, V] fp32
    const float* temps  = (const float*)d_in[1];   // [B]    fp32
    const float* noise  = (const float*)d_in[2];   // [B, V] fp32
    int* out = (int*)d_out;                        // [B]    int32

    // workspace layout: B*SPLITS floats (partial maxes) then B*SPLITS ints
    float* pmax = (float*)d_ws;
    int*   pidx = (int*)((char*)d_ws + sizeof(float) * BB * SPLITS);

    sampler_partial<<<BB * SPLITS, TPB, 0, stream>>>(logits, temps, noise, pmax, pidx);
    sampler_reduce<<<1, 128, 0, stream>>>(pmax, pidx, out);
}

// Round 2
// 141.773 us; speedup vs baseline: 1.0165x; 1.0165x over previous
//
#include <hip/hip_runtime.h>
#include <cstdint>
#include <math.h>

// B=128 rows, V=128000 vocab. fp32 logits/noise/temps -> int32 argmax index.
#define BB 128
#define VV 128000
#define SPLITS 25                // 128000/25 = 5120 = 256 threads * 20 elems EXACT
#define CHUNK (VV / SPLITS)      // 5120
#define TPB 256
#define ITERS 5                  // float4 iterations per thread: 5*4 = 20 elems

// Map fp32 to order-preserving uint32 (no NaNs in this problem).
__device__ __forceinline__ uint32_t sortable(float f) {
    uint32_t u = __float_as_uint(f);
    return (u & 0x80000000u) ? ~u : (u | 0x80000000u);
}

__device__ __forceinline__ uint64_t kmax(uint64_t a, uint64_t b) {
    return a > b ? a : b;
}

__global__ __launch_bounds__(TPB) void sampler_partial(
    const float* __restrict__ logits,
    const float* __restrict__ temps,
    const float* __restrict__ noise,
    uint64_t* __restrict__ pkey)
{
    const int blk = blockIdx.x;
    const int row = blk / SPLITS;
    const int seg = blk % SPLITS;

    const float t = temps[row];
    const bool greedy = (t == 0.0f);           // block-uniform branch
    const float invt = greedy ? 1.0f : (1.0f / t);

    const float* lrow = logits + (size_t)row * VV + seg * CHUNK;
    const float* nrow = noise  + (size_t)row * VV + seg * CHUNK;

    const int base = (int)threadIdx.x * 4;     // coalesced float4 across threads

    // Issue all logits loads up front (5 float4 = 80 B/lane in flight).
    float4 l[ITERS];
    #pragma unroll
    for (int j = 0; j < ITERS; ++j)
        l[j] = *reinterpret_cast<const float4*>(lrow + base + j * (TPB * 4));

    float bv = -INFINITY;
    int   bi = 0;

    if (greedy) {
        #pragma unroll
        for (int j = 0; j < ITERS; ++j) {
            const int i0 = seg * CHUNK + base + j * (TPB * 4);
            const float v[4] = { l[j].x, l[j].y, l[j].z, l[j].w };
            #pragma unroll
            for (int c = 0; c < 4; ++c) {
                // ascending index + strict '>' keeps FIRST occurrence
                if (v[c] > bv) { bv = v[c]; bi = i0 + c; }
            }
        }
    } else {
        float4 e[ITERS];
        #pragma unroll
        for (int j = 0; j < ITERS; ++j)
            e[j] = *reinterpret_cast<const float4*>(nrow + base + j * (TPB * 4));
        #pragma unroll
        for (int j = 0; j < ITERS; ++j) {
            const int i0 = seg * CHUNK + base + j * (TPB * 4);
            const float lv[4] = { l[j].x, l[j].y, l[j].z, l[j].w };
            const float ev[4] = { e[j].x, e[j].y, e[j].z, e[j].w };
            #pragma unroll
            for (int c = 0; c < 4; ++c) {
                const float s = lv[c] * invt - logf(fmaxf(ev[c], 1e-10f));
                if (s > bv) { bv = s; bi = i0 + c; }
            }
        }
    }

    // Pack (value, ~index): u64 max == argmax with smallest-index tie-break.
    uint64_t key = ((uint64_t)sortable(bv) << 32) | (uint32_t)(~(uint32_t)bi);

    // wave64 shuffle reduction
    #pragma unroll
    for (int off = 32; off > 0; off >>= 1) {
        uint64_t ok = __shfl_down(key, off, 64);
        key = kmax(key, ok);
    }

    __shared__ uint64_t sk[TPB / 64];
    const int lane = threadIdx.x & 63;
    const int wave = threadIdx.x >> 6;
    if (lane == 0) sk[wave] = key;
    __syncthreads();
    if (threadIdx.x == 0) {
        #pragma unroll
        for (int w = 1; w < TPB / 64; ++w) key = kmax(key, sk[w]);
        pkey[blk] = key;
    }
}

__global__ __launch_bounds__(BB) void sampler_reduce(
    const uint64_t* __restrict__ pkey,
    int* __restrict__ out)
{
    const int r = threadIdx.x;                 // 128 threads, 1 block
    uint64_t key = pkey[r * SPLITS];
    #pragma unroll
    for (int s = 1; s < SPLITS; ++s)
        key = kmax(key, pkey[r * SPLITS + s]);
    out[r] = (int)(~(uint32_t)(key & 0xffffffffu));
}

extern "C" void kernel_launch(void* const* d_in, const int* in_sizes, int n_in,
                              void* d_out, int out_size, void* d_ws, size_t ws_size,
                              hipStream_t stream) {
    const float* logits = (const float*)d_in[0];   // [B, V] fp32
    const float* temps  = (const float*)d_in[1];   // [B]    fp32
    const float* noise  = (const float*)d_in[2];   // [B, V] fp32
    int* out = (int*)d_out;                        // [B]    int32

    uint64_t* pkey = (uint64_t*)d_ws;              // BB*SPLITS u64 = 25.6 KB

    sampler_partial<<<BB * SPLITS, TPB, 0, stream>>>(logits, temps, noise, pkey);
    sampler_reduce<<<1, BB, 0, stream>>>(pkey, out);
}